// Round 6
// baseline (1005.565 us; speedup 1.0000x reference)
//
#include <hip/hip_runtime.h>
#include <hip/hip_bf16.h>
#include <math.h>

#define BB 8192
#define SS 64
#define HH 320
#define EE 4
#define KK 2
#define ROUTES (BB * KK)          // 16384
#define CAPACITY 5120             // ceil(1.25 * 8192 * 2 / 4)
#define EPSF 1e-9f

// ---------------------------------------------------------------------------
// Kernel A: masked mean-pool + router (softmax, top-2) per batch row.
// grid = 8192 blocks, block = 320 threads (5 waves).
// Also zeroes the rank array (blocks 0..63).
// ---------------------------------------------------------------------------
__global__ __launch_bounds__(320) void pool_router_kernel(
    const float* __restrict__ hidden,       // [B,S,H]
    const int*   __restrict__ mask,         // [B,S]
    const float* __restrict__ router_w,     // [E,H]
    const float* __restrict__ router_b,     // [E]
    float* __restrict__ pooled,             // [B,H] out
    float* __restrict__ vals,               // [B*K] out (raw top-k probs)
    int*   __restrict__ ex,                 // [B*K] out (expert idx)
    float* __restrict__ tw,                 // [B*K] out (normalized top-k weight)
    int*   __restrict__ rank)               // [ROUTES] zeroed here
{
    const int b = blockIdx.x;
    const int t = threadIdx.x;

    __shared__ float maskf[SS];
    __shared__ float pooled_s[HH];
    __shared__ float4 part[4][80];
    __shared__ float logits_s[EE];
    __shared__ float msum_s;

    // zero rank[] (ws is re-poisoned to 0xAA before every timed call)
    if (b < 64 && t < 256) rank[b * 256 + t] = 0;

    if (t < SS) maskf[t] = (float)mask[(size_t)b * SS + t];
    __syncthreads();

    if (t < 64) {
        float m = maskf[t];
        #pragma unroll
        for (int o = 32; o > 0; o >>= 1) m += __shfl_down(m, o, 64);
        if (t == 0) msum_s = m;
    }

    // ---- pooling: H = 320 floats = 80 float4 columns; 4 s-groups of 16 ----
    const int c = t % 80;
    const int g = t / 80;
    const float4* hp = (const float4*)(hidden + (size_t)b * (SS * HH));
    float4 acc = make_float4(0.f, 0.f, 0.f, 0.f);
    const int s0 = g * 16;
    #pragma unroll
    for (int i = 0; i < 16; ++i) {
        float4 v = hp[(size_t)(s0 + i) * 80 + c];
        float m = maskf[s0 + i];
        acc.x = fmaf(v.x, m, acc.x);
        acc.y = fmaf(v.y, m, acc.y);
        acc.z = fmaf(v.z, m, acc.z);
        acc.w = fmaf(v.w, m, acc.w);
    }
    part[g][c] = acc;
    __syncthreads();

    if (t < 80) {
        float4 a0 = part[0][t], a1 = part[1][t], a2 = part[2][t], a3 = part[3][t];
        float inv = 1.0f / fmaxf(msum_s, EPSF);
        float4 p;
        p.x = (a0.x + a1.x + a2.x + a3.x) * inv;
        p.y = (a0.y + a1.y + a2.y + a3.y) * inv;
        p.z = (a0.z + a1.z + a2.z + a3.z) * inv;
        p.w = (a0.w + a1.w + a2.w + a3.w) * inv;
        ((float4*)pooled)[(size_t)b * 80 + t] = p;
        pooled_s[t * 4 + 0] = p.x;
        pooled_s[t * 4 + 1] = p.y;
        pooled_s[t * 4 + 2] = p.z;
        pooled_s[t * 4 + 3] = p.w;
    }
    __syncthreads();

    // ---- router logits: 4 experts, one wave each ----
    if (t < 256) {
        const int e = t >> 6;
        const int lane = t & 63;
        float sum = 0.f;
        #pragma unroll
        for (int i = 0; i < 5; ++i) {
            int h = lane + 64 * i;
            sum = fmaf(pooled_s[h], router_w[e * HH + h], sum);
        }
        #pragma unroll
        for (int o = 32; o > 0; o >>= 1) sum += __shfl_down(sum, o, 64);
        if (lane == 0) logits_s[e] = sum + router_b[e];
    }
    __syncthreads();

    // ---- softmax + top-2 (ties -> lower index, matches lax.top_k) ----
    if (t == 0) {
        float mx = logits_s[0];
        #pragma unroll
        for (int e = 1; e < EE; ++e) mx = fmaxf(mx, logits_s[e]);
        float pr[EE];
        float den = 0.f;
        #pragma unroll
        for (int e = 0; e < EE; ++e) { pr[e] = expf(logits_s[e] - mx); den += pr[e]; }
        #pragma unroll
        for (int e = 0; e < EE; ++e) pr[e] /= den;

        int i0 = 0;
        #pragma unroll
        for (int e = 1; e < EE; ++e) if (pr[e] > pr[i0]) i0 = e;
        int i1 = -1;
        #pragma unroll
        for (int e = 0; e < EE; ++e) {
            if (e == i0) continue;
            if (i1 < 0 || pr[e] > pr[i1]) i1 = e;
        }
        float v0 = pr[i0], v1 = pr[i1];
        float tsum = fmaxf(v0 + v1, EPSF);
        vals[b * 2 + 0] = v0;
        vals[b * 2 + 1] = v1;
        ex[b * 2 + 0] = i0;
        ex[b * 2 + 1] = i1;
        tw[b * 2 + 0] = v0 / tsum;
        tw[b * 2 + 1] = v1 / tsum;
    }
}

// ---------------------------------------------------------------------------
// Kernel B: dense per-expert MLP -> expert_out[b,e].
// grid = 256 blocks (32 b-rows each), block = 512 threads (one (e,f) column
// per thread, 32 accumulators register-blocked over the b-tile).
// ---------------------------------------------------------------------------
__global__ __launch_bounds__(512) void mlp_kernel(
    const float* __restrict__ pooled,   // [B,H]
    const float* __restrict__ w1,       // [E,H,128]
    const float* __restrict__ b1,       // [E,128]
    const float* __restrict__ w2,       // [E,128]
    const float* __restrict__ b2,       // [E]
    float* __restrict__ exout)          // [B,E]
{
    __shared__ float pl[32][HH];        // 40 KB
    __shared__ float wsum[8][32];

    const int t = threadIdx.x;
    const int bb = blockIdx.x * 32;

    // stage pooled tile (contiguous 32*320 floats)
    {
        const float4* src = (const float4*)(pooled + (size_t)bb * HH);
        float4* dst = (float4*)(&pl[0][0]);
        #pragma unroll
        for (int i = 0; i < 5; ++i) dst[t + i * 512] = src[t + i * 512];
    }
    __syncthreads();

    const int e = t >> 7;
    const int f = t & 127;
    const float* w1p = w1 + (size_t)e * (HH * 128) + f;

    float acc[32];
    #pragma unroll
    for (int j = 0; j < 32; ++j) acc[j] = 0.f;

    for (int h = 0; h < HH; h += 4) {
        float wv0 = w1p[(size_t)(h + 0) * 128];
        float wv1 = w1p[(size_t)(h + 1) * 128];
        float wv2 = w1p[(size_t)(h + 2) * 128];
        float wv3 = w1p[(size_t)(h + 3) * 128];
        #pragma unroll
        for (int j = 0; j < 32; ++j) {
            float4 p = *(const float4*)(&pl[j][h]);   // wave-uniform broadcast
            acc[j] = fmaf(p.x, wv0, acc[j]);
            acc[j] = fmaf(p.y, wv1, acc[j]);
            acc[j] = fmaf(p.z, wv2, acc[j]);
            acc[j] = fmaf(p.w, wv3, acc[j]);
        }
    }

    const float b1v = b1[e * 128 + f];
    const float w2v = w2[e * 128 + f];
    const int wid = t >> 6, lane = t & 63;

    #pragma unroll
    for (int j = 0; j < 32; ++j) {
        float v = fmaxf(acc[j] + b1v, 0.f) * w2v;
        #pragma unroll
        for (int o = 32; o > 0; o >>= 1) v += __shfl_down(v, o, 64);
        if (lane == 0) wsum[wid][j] = v;
    }
    __syncthreads();

    if (t < 128) {
        int j = t & 31, e2 = t >> 5;
        float v = wsum[2 * e2][j] + wsum[2 * e2 + 1][j] + b2[e2];
        exout[(size_t)(bb + j) * EE + e2] = v;
    }
}

// ---------------------------------------------------------------------------
// Kernel C: capacity assignment. rank(r) = #{r' : e'==e && (v'>v || (v'==v
// && r'<r))} — identical to stable sort-by-(-v) + per-expert cumsum.
// grid = (64 route-blocks, 16 chunks), block = 256.
// ---------------------------------------------------------------------------
#define CSZ 1024
__global__ __launch_bounds__(256) void rank_kernel(
    const float* __restrict__ vals,
    const int*   __restrict__ ex,
    int* __restrict__ rank)
{
    __shared__ float vv[CSZ];
    __shared__ int   ee[CSZ];

    const int r = blockIdx.x * 256 + threadIdx.x;
    const float v = vals[r];
    const int   e = ex[r];
    const int cbase = blockIdx.y * CSZ;

    for (int i = threadIdx.x; i < CSZ; i += 256) {
        vv[i] = vals[cbase + i];
        ee[i] = ex[cbase + i];
    }
    __syncthreads();

    int cnt = 0;
    #pragma unroll 8
    for (int i = 0; i < CSZ; ++i) {
        int rp = cbase + i;
        bool higher = (vv[i] > v) || (vv[i] == v && rp < r);
        cnt += (ee[i] == e && higher) ? 1 : 0;
    }
    atomicAdd(&rank[r], cnt);
}

// ---------------------------------------------------------------------------
// Kernel D: merge accepted routes -> scores[B].
// ---------------------------------------------------------------------------
__global__ __launch_bounds__(256) void merge_kernel(
    const float* __restrict__ tw,
    const int*   __restrict__ ex,
    const int*   __restrict__ rank,
    const float* __restrict__ exout,
    float* __restrict__ out)
{
    const int b = blockIdx.x * 256 + threadIdx.x;
    float w0 = tw[b * 2 + 0], w1v = tw[b * 2 + 1];
    float aw0 = (rank[b * 2 + 0] < CAPACITY) ? w0 : 0.f;
    float aw1 = (rank[b * 2 + 1] < CAPACITY) ? w1v : 0.f;
    float den = fmaxf(aw0 + aw1, EPSF);
    float rs0 = exout[(size_t)b * EE + ex[b * 2 + 0]];
    float rs1 = exout[(size_t)b * EE + ex[b * 2 + 1]];
    out[b] = (aw0 * rs0 + aw1 * rs1) / den;
}

// ---------------------------------------------------------------------------
extern "C" void kernel_launch(void* const* d_in, const int* in_sizes, int n_in,
                              void* d_out, int out_size, void* d_ws, size_t ws_size,
                              hipStream_t stream) {
    const float* hidden   = (const float*)d_in[0];
    const int*   mask     = (const int*)d_in[1];
    const float* router_w = (const float*)d_in[2];
    const float* router_b = (const float*)d_in[3];
    const float* w1       = (const float*)d_in[4];
    const float* b1       = (const float*)d_in[5];
    const float* w2       = (const float*)d_in[6];
    const float* b2       = (const float*)d_in[7];
    float* out = (float*)d_out;

    char* w = (char*)d_ws;
    float* pooled = (float*)(w);                         // B*H f32 = 10,485,760 B
    float* vals   = (float*)(w + 10485760);              // 16384 f32
    float* tw     = (float*)(w + 10485760 + 65536);      // 16384 f32
    int*   exI    = (int*)  (w + 10485760 + 131072);     // 16384 i32
    int*   rank   = (int*)  (w + 10485760 + 196608);     // 16384 i32
    float* exout  = (float*)(w + 10485760 + 262144);     // B*E f32 = 131,072 B

    pool_router_kernel<<<BB, 320, 0, stream>>>(hidden, mask, router_w, router_b,
                                               pooled, vals, exI, tw, rank);
    mlp_kernel<<<BB / 32, 512, 0, stream>>>(pooled, w1, b1, w2, b2, exout);
    rank_kernel<<<dim3(ROUTES / 256, ROUTES / CSZ), 256, 0, stream>>>(vals, exI, rank);
    merge_kernel<<<BB / 256, 256, 0, stream>>>(tw, exI, rank, exout, out);
}